// Round 8
// baseline (311.171 us; speedup 1.0000x reference)
//
#include <hip/hip_runtime.h>
#include <hip/hip_bf16.h>

typedef unsigned short u16;
typedef unsigned int   u32;
typedef __attribute__((ext_vector_type(8))) short  s16x8;
typedef __attribute__((ext_vector_type(4))) float  f32x4;
typedef __attribute__((ext_vector_type(4))) unsigned short u16x4;

#define MT    8192   // B*S tokens
#define DE    2048   // embed dim
#define NEXP  64     // experts
#define ERDIM 4096   // experts * rank

// round-to-nearest-even f32 -> bf16
__device__ __forceinline__ u16 to_bf16(float f) {
  u32 u = __builtin_bit_cast(u32, f);
  u32 r = u + 0x7fffu + ((u >> 16) & 1u);
  return (u16)(r >> 16);
}

__global__ void cvt_f32_bf16(const float* __restrict__ in, u16* __restrict__ out, int n) {
  const int stride = gridDim.x * blockDim.x;
  for (int i = blockIdx.x * blockDim.x + threadIdx.x; i * 4 < n; i += stride) {
    const float4 v = *reinterpret_cast<const float4*>(in + (size_t)i * 4);
    u16x4 o;
    o.x = to_bf16(v.x); o.y = to_bf16(v.y); o.z = to_bf16(v.z); o.w = to_bf16(v.w);
    *reinterpret_cast<u16x4*>(out + (size_t)i * 4) = o;
  }
}

#define GLDS(gp, lp) __builtin_amdgcn_global_load_lds(                        \
    (const __attribute__((address_space(1))) void*)(gp),                      \
    (__attribute__((address_space(3))) void*)(lp), 16, 0, 0)

#define BAR() do { asm volatile("" ::: "memory");                             \
                   __builtin_amdgcn_s_barrier();                              \
                   asm volatile("" ::: "memory"); } while (0)

// C = A[M,K] * B[N,K]^T (bf16, row-major). 256x128 tile, BK=32, 8 waves (4Mx2N,
// 64x64 each), 16x16x32 MFMA. 3-slot LDS ring (72 KiB -> 2 blocks/CU), prefetch
// distance 2, counted vmcnt (never 0 mid-loop), ONE barrier per K-tile,
// free-running waves (R3-proven structure; this round only shrinks footprint
// for occupancy). Proven conflict-free granule swizzle: linear LDS dest
// (global_load_lds) + inverse-swizzled global src + matching read XOR.
// Slot safety: slot read at tile t is overwritten by GLDS issued at t+2,
// separated by barrier(t)+MFMA(t+1) -- same margin as validated R3 ring.
// FUSE=1: C_bf16[m,n] = bf16( silu(acc) * mask[m, n>>6] );  FUSE=0: C_f32 = acc
template<int FUSE, int K>
__global__ __launch_bounds__(512, 4) void gemm_bt(
    const u16* __restrict__ A, const u16* __restrict__ Bm,
    const float* __restrict__ mask, void* __restrict__ Cout,
    const int M, const int N)
{
  constexpr int BM = 256, BN = 128, BK = 32;
  constexpr int NT = K / BK;
  constexpr int SLOT = 12288;                // elems: A 8192 + B 4096
  __shared__ __align__(16) u16 lds[3 * SLOT];  // 72 KiB

  const int nbn = N / BN;
  const int nwg = (int)gridDim.x;
  const int cpx = nwg >> 3;                      // nwg % 8 == 0 for all our grids
  const int bid = (int)blockIdx.x;
  const int swz = (bid & 7) * cpx + (bid >> 3);  // bijective XCD swizzle
  const int bm = (swz / nbn) * BM;
  const int bn = (swz % nbn) * BN;

  const int tid  = (int)threadIdx.x;
  const int lane = tid & 63;
  const int w    = tid >> 6;       // wave 0..7
  const int wr   = w >> 1;         // 0..3: M row-group (64 rows)
  const int wc   = w & 1;          // 0..1: N col-group (64 cols)

  const int fr = lane & 15;                          // fragment row
  const int cp = (lane >> 4) ^ ((lane >> 1) & 3);    // swizzled granule col (read)

  // staging: thread covers row w*16 + lane/4, inverse-swizzled source granule.
  // A: 2 rounds (rows +0, +128). B: 1 round (rows 0..127).
  const int r0 = w * 16 + (lane >> 2);
  const int cl = (lane & 3) ^ ((lane >> 3) & 3);
  const u16* aS0 = A  + (size_t)(bm + r0) * K + cl * 8;
  const u16* aS1 = A  + (size_t)(bm + r0 + 128) * K + cl * 8;
  const u16* bS0 = Bm + (size_t)(bn + r0) * K + cl * 8;
  const int d0 = w * 512;          // wave-uniform LDS elem offset per round

  f32x4 acc[4][4] = {};

  // ---- prologue: stage tiles 0,1 (3 GLDS each) ----
#pragma unroll
  for (int t = 0; t < 2; ++t) {
    u16* dst = lds + t * SLOT;
    GLDS(aS0 + t * BK, dst +        d0);
    GLDS(aS1 + t * BK, dst + 4096 + d0);
    GLDS(bS0 + t * BK, dst + 8192 + d0);
  }
  asm volatile("s_waitcnt vmcnt(3)" ::: "memory");   // tile 0 landed; 1 in flight
  BAR();

  // ---- main loop: one barrier per K-tile, free-running otherwise ----
  int ro = 0;             // read-slot elem offset: (t%3)*SLOT
  int so = 2 * SLOT;      // stage-slot elem offset: ((t+2)%3)*SLOT
#pragma unroll 3
  for (int t = 0; t < NT; ++t) {
    const u16* sA = lds + ro;
    const u16* sB = lds + ro + 8192;

    // [1] fragment reads for tile t (8 x ds_read_b128, conflict-free)
    s16x8 afr[4], bfr[4];
#pragma unroll
    for (int m = 0; m < 4; ++m)
      afr[m] = *reinterpret_cast<const s16x8*>(
          &sA[(wr * 64 + m * 16 + fr) * 32 + cp * 8]);
#pragma unroll
    for (int n = 0; n < 4; ++n)
      bfr[n] = *reinterpret_cast<const s16x8*>(
          &sB[(wc * 64 + n * 16 + fr) * 32 + cp * 8]);

    // [2] stage tile t+2
    if (t + 2 < NT) {
      u16* dst = lds + so;
      const size_t koff = (size_t)(t + 2) * BK;
      GLDS(aS0 + koff, dst +        d0);
      GLDS(aS1 + koff, dst + 4096 + d0);
      GLDS(bS0 + koff, dst + 8192 + d0);
    }

    // [3] MFMA cluster for tile t
    __builtin_amdgcn_s_setprio(1);
#pragma unroll
    for (int m = 0; m < 4; ++m)
#pragma unroll
      for (int n = 0; n < 4; ++n)
        acc[m][n] = __builtin_amdgcn_mfma_f32_16x16x32_bf16(
            afr[m], bfr[n], acc[m][n], 0, 0, 0);
    __builtin_amdgcn_s_setprio(0);

    // [4] counted tile-boundary drain: tile t+1 landed before next reads
    if (t + 2 < NT)      asm volatile("s_waitcnt vmcnt(3)" ::: "memory");
    else if (t + 1 < NT) asm volatile("s_waitcnt vmcnt(0)" ::: "memory");

    // [5] barrier: cross-wave landing guarantee + slot-reuse fence
    if (t + 1 < NT) BAR();

    ro = (ro == 2 * SLOT) ? 0 : ro + SLOT;
    so = (so == 2 * SLOT) ? 0 : so + SLOT;
  }

  // ---- epilogue: C/D layout col=lane&15, row=(lane>>4)*4 + j ----
  const int rgrp = (lane >> 4) * 4;
  if (FUSE) {
    u16* H = (u16*)Cout;
    const int ew = (bn + wc * 64) >> 6;  // wave's 64-col span = exactly one expert
#pragma unroll
    for (int m = 0; m < 4; ++m) {
#pragma unroll
      for (int j = 0; j < 4; ++j) {
        const int grow = bm + wr * 64 + m * 16 + rgrp + j;
        const float mv = mask[(size_t)grow * NEXP + ew];
#pragma unroll
        for (int n = 0; n < 4; ++n) {
          const int gcol = bn + wc * 64 + n * 16 + fr;
          float v = acc[m][n][j];
          v = v / (1.0f + __expf(-v));   // silu
          H[(size_t)grow * N + gcol] = to_bf16(v * mv);
        }
      }
    }
  } else {
    float* O = (float*)Cout;
#pragma unroll
    for (int m = 0; m < 4; ++m) {
#pragma unroll
      for (int j = 0; j < 4; ++j) {
        const int grow = bm + wr * 64 + m * 16 + rgrp + j;
#pragma unroll
        for (int n = 0; n < 4; ++n) {
          const int gcol = bn + wc * 64 + n * 16 + fr;
          O[(size_t)grow * N + gcol] = acc[m][n][j];
        }
      }
    }
  }
}

extern "C" void kernel_launch(void* const* d_in, const int* in_sizes, int n_in,
                              void* d_out, int out_size, void* d_ws, size_t ws_size,
                              hipStream_t stream) {
  const float* x     = (const float*)d_in[0];
  const float* emask = (const float*)d_in[1];
  const float* w_up  = (const float*)d_in[2];
  const float* w_dn  = (const float*)d_in[3];
  float* out = (float*)d_out;

  // workspace (bf16): x[8192,2048] | w_up[4096,2048] | w_dn[2048,4096] | H[8192,4096]
  const size_t need = ((size_t)MT * DE + (size_t)ERDIM * DE + (size_t)DE * ERDIM +
                       (size_t)MT * ERDIM) * sizeof(u16);
  if (ws_size < need) return;

  u16* xb  = (u16*)d_ws;
  u16* wub = xb  + (size_t)MT * DE;
  u16* wdb = wub + (size_t)ERDIM * DE;
  u16* hb  = wdb + (size_t)DE * ERDIM;

  hipLaunchKernelGGL(cvt_f32_bf16, dim3(2048), dim3(256), 0, stream, x,    xb,  MT * DE);
  hipLaunchKernelGGL(cvt_f32_bf16, dim3(1024), dim3(256), 0, stream, w_up, wub, ERDIM * DE);
  hipLaunchKernelGGL(cvt_f32_bf16, dim3(1024), dim3(256), 0, stream, w_dn, wdb, DE * ERDIM);

  // GEMM1: H = silu(X @ Wup^T) * mask   [M=8192, N=4096, K=2048] -> 1024 blocks
  hipLaunchKernelGGL((gemm_bt<1, DE>), dim3((MT / 256) * (ERDIM / 128)), dim3(512), 0, stream,
                     xb, wub, emask, (void*)hb, MT, ERDIM);
  // GEMM2: out = H @ Wdown^T             [M=8192, N=2048, K=4096] -> 512 blocks
  hipLaunchKernelGGL((gemm_bt<0, ERDIM>), dim3((MT / 256) * (DE / 128)), dim3(512), 0, stream,
                     hb, wdb, nullptr, (void*)out, MT, DE);
}

// Round 9
// 290.330 us; speedup vs baseline: 1.0718x; 1.0718x over previous
//
#include <hip/hip_runtime.h>
#include <hip/hip_bf16.h>

typedef unsigned short u16;
typedef unsigned int   u32;
typedef __attribute__((ext_vector_type(8))) short  s16x8;
typedef __attribute__((ext_vector_type(4))) float  f32x4;
typedef __attribute__((ext_vector_type(4))) unsigned short u16x4;

#define MT    8192   // B*S tokens
#define DE    2048   // embed dim
#define NEXP  64     // experts
#define ERDIM 4096   // experts * rank

// round-to-nearest-even f32 -> bf16
__device__ __forceinline__ u16 to_bf16(float f) {
  u32 u = __builtin_bit_cast(u32, f);
  u32 r = u + 0x7fffu + ((u >> 16) & 1u);
  return (u16)(r >> 16);
}

__global__ void cvt_f32_bf16(const float* __restrict__ in, u16* __restrict__ out, int n) {
  const int stride = gridDim.x * blockDim.x;
  for (int i = blockIdx.x * blockDim.x + threadIdx.x; i * 4 < n; i += stride) {
    const float4 v = *reinterpret_cast<const float4*>(in + (size_t)i * 4);
    u16x4 o;
    o.x = to_bf16(v.x); o.y = to_bf16(v.y); o.z = to_bf16(v.z); o.w = to_bf16(v.w);
    *reinterpret_cast<u16x4*>(out + (size_t)i * 4) = o;
  }
}

#define GLDS(gp, lp) __builtin_amdgcn_global_load_lds(                        \
    (const __attribute__((address_space(1))) void*)(gp),                      \
    (__attribute__((address_space(3))) void*)(lp), 16, 0, 0)

#define BAR() do { asm volatile("" ::: "memory");                             \
                   __builtin_amdgcn_s_barrier();                              \
                   asm volatile("" ::: "memory"); } while (0)

// C = A[M,K] * B[N,K]^T (bf16, row-major). 256x256 tile, BK=32, 8 waves (2Mx4N),
// 16x16x32 MFMA, 4-slot LDS ring, prefetch distance 3, counted vmcnt
// (8/4/0 cascade, never 0 mid-loop), ONE barrier per K-tile (R3 skeleton).
// NEW: half-tile software pipeline across the barrier. Per interval:
//   [8 ds_read a0-3(t)+b(t)] [GLDS t+3] [16 MFMA half2(t-1): a1_old x b_old,
//   NO lgkm dep -> issues immediately, covers the in-flight reads]
//   [4 ds_read a4-7(t)] [16 MFMA half1(t)] [vmcnt] [BAR]
// Cross-barrier liveness: 8 frags (a1 + b_cur, 32 VGPR) - R6-proven no-spill.
// Slot safety identical to R3 (GLDS(t+3) targets slot (t-1)&3, readers done
// before barrier(t-1)). LDS swizzle: linear dest + inverse-swizzled global
// source + matching read XOR (0 conflicts measured since R2).
// FUSE=1: C_bf16[m,n] = bf16( silu(acc) * mask[m, n>>6] );  FUSE=0: C_f32 = acc
template<int FUSE, int K>
__global__ __launch_bounds__(512, 2) void gemm_bt(
    const u16* __restrict__ A, const u16* __restrict__ Bm,
    const float* __restrict__ mask, void* __restrict__ Cout,
    const int M, const int N)
{
  constexpr int BM = 256, BN = 256, BK = 32;
  constexpr int NT = K / BK;
  __shared__ __align__(16) u16 lds[65536];   // 4 slots x (A 8K elem + B 8K elem)

  const int nbn = N / BN;
  const int nwg = (int)gridDim.x;
  const int cpx = nwg >> 3;                      // nwg % 8 == 0 for all our grids
  const int bid = (int)blockIdx.x;
  const int swz = (bid & 7) * cpx + (bid >> 3);  // bijective XCD swizzle
  const int bm = (swz / nbn) * BM;
  const int bn = (swz % nbn) * BN;

  const int tid  = (int)threadIdx.x;
  const int lane = tid & 63;
  const int w    = tid >> 6;       // wave 0..7
  const int wr   = w >> 2;         // 0..1: M row-group (128 rows)
  const int wc   = w & 3;          // 0..3: N col-group (64 cols)

  const int fr = lane & 15;                          // fragment row
  const int cp = (lane >> 4) ^ ((lane >> 1) & 3);    // swizzled granule col (read)

  // staging: wave w owns chunks {2w, 2w+1} (16 rows x 64B each) of both A and B.
  // linear LDS dest (global_load_lds) + inverse-swizzled per-lane global source.
  const int lr = lane >> 2;                          // row within chunk
  const int cl = (lane & 3) ^ ((lane >> 3) & 3);     // logical granule col (source)
  const int c0 = 2 * w, c1 = 2 * w + 1;
  const u16* aS0 = A  + (size_t)(bm + c0 * 16 + lr) * K + cl * 8;
  const u16* aS1 = A  + (size_t)(bm + c1 * 16 + lr) * K + cl * 8;
  const u16* bS0 = Bm + (size_t)(bn + c0 * 16 + lr) * K + cl * 8;
  const u16* bS1 = Bm + (size_t)(bn + c1 * 16 + lr) * K + cl * 8;

  f32x4 acc[8][4] = {};

  // ---- prologue: stage tiles 0,1,2 ----
#pragma unroll
  for (int t = 0; t < 3; ++t) {
    u16* dst = lds + t * 16384;
    GLDS(aS0 + t * BK, dst +        c0 * 512);
    GLDS(aS1 + t * BK, dst +        c1 * 512);
    GLDS(bS0 + t * BK, dst + 8192 + c0 * 512);
    GLDS(bS1 + t * BK, dst + 8192 + c1 * 512);
  }
  asm volatile("s_waitcnt vmcnt(8)" ::: "memory");   // tile 0 landed; 1,2 in flight
  BAR();

  s16x8 a0[4], a1[4], b0[4], b1[4];

  // ---- pipeline prologue: tile 0 (reads + half1 MFMA; a1,b0 carried) ----
  {
    const u16* sA = lds;
    const u16* sB = lds + 8192;
#pragma unroll
    for (int m = 0; m < 4; ++m)
      a0[m] = *reinterpret_cast<const s16x8*>(
          &sA[(wr * 128 + m * 16 + fr) * 32 + cp * 8]);
#pragma unroll
    for (int n = 0; n < 4; ++n)
      b0[n] = *reinterpret_cast<const s16x8*>(
          &sB[(wc * 64 + n * 16 + fr) * 32 + cp * 8]);
#pragma unroll
    for (int m = 0; m < 4; ++m)
      a1[m] = *reinterpret_cast<const s16x8*>(
          &sA[(wr * 128 + (4 + m) * 16 + fr) * 32 + cp * 8]);
    u16* dst = lds + 3 * 16384;   // stage tile 3 (slot 3)
    GLDS(aS0 + 3 * BK, dst +        c0 * 512);
    GLDS(aS1 + 3 * BK, dst +        c1 * 512);
    GLDS(bS0 + 3 * BK, dst + 8192 + c0 * 512);
    GLDS(bS1 + 3 * BK, dst + 8192 + c1 * 512);
    __builtin_amdgcn_s_setprio(1);
#pragma unroll
    for (int m = 0; m < 4; ++m)
#pragma unroll
      for (int n = 0; n < 4; ++n)
        acc[m][n] = __builtin_amdgcn_mfma_f32_16x16x32_bf16(
            a0[m], b0[n], acc[m][n], 0, 0, 0);
    __builtin_amdgcn_s_setprio(0);
    asm volatile("s_waitcnt vmcnt(8)" ::: "memory");   // tile 1 landed
    BAR();
  }

// BODY(T): one K-tile interval. BIN = b-frags of tile T-1 (live), BOUT = b-frags
// of tile T (written). a1 on entry = a4-7(T-1); on exit = a4-7(T).
#define BODY(T, BIN, BOUT, LAST)                                              \
  {                                                                           \
    const u16* sA = lds + ((T) & 3) * 16384;                                  \
    const u16* sB = sA + 8192;                                                \
    _Pragma("unroll")                                                         \
    for (int m = 0; m < 4; ++m)                                               \
      a0[m] = *reinterpret_cast<const s16x8*>(                                \
          &sA[(wr * 128 + m * 16 + fr) * 32 + cp * 8]);                       \
    _Pragma("unroll")                                                         \
    for (int n = 0; n < 4; ++n)                                               \
      BOUT[n] = *reinterpret_cast<const s16x8*>(                              \
          &sB[(wc * 64 + n * 16 + fr) * 32 + cp * 8]);                        \
    if ((T) + 3 < NT) {                                                       \
      u16* dst = lds + (((T) + 3) & 3) * 16384;                               \
      const size_t koff = (size_t)((T) + 3) * BK;                             \
      GLDS(aS0 + koff, dst +        c0 * 512);                                \
      GLDS(aS1 + koff, dst +        c1 * 512);                                \
      GLDS(bS0 + koff, dst + 8192 + c0 * 512);                                \
      GLDS(bS1 + koff, dst + 8192 + c1 * 512);                                \
    }                                                                         \
    __builtin_amdgcn_s_setprio(1);                                            \
    _Pragma("unroll")                                                         \
    for (int m = 0; m < 4; ++m)                                               \
      _Pragma("unroll")                                                       \
      for (int n = 0; n < 4; ++n)                                             \
        acc[4 + m][n] = __builtin_amdgcn_mfma_f32_16x16x32_bf16(              \
            a1[m], BIN[n], acc[4 + m][n], 0, 0, 0);                           \
    __builtin_amdgcn_s_setprio(0);                                            \
    _Pragma("unroll")                                                         \
    for (int m = 0; m < 4; ++m)                                               \
      a1[m] = *reinterpret_cast<const s16x8*>(                                \
          &sA[(wr * 128 + (4 + m) * 16 + fr) * 32 + cp * 8]);                 \
    __builtin_amdgcn_s_setprio(1);                                            \
    _Pragma("unroll")                                                         \
    for (int m = 0; m < 4; ++m)                                               \
      _Pragma("unroll")                                                       \
      for (int n = 0; n < 4; ++n)                                             \
        acc[m][n] = __builtin_amdgcn_mfma_f32_16x16x32_bf16(                  \
            a0[m], BOUT[n], acc[m][n], 0, 0, 0);                              \
    __builtin_amdgcn_s_setprio(0);                                            \
    if (!(LAST)) {                                                            \
      if ((T) + 3 < NT)      asm volatile("s_waitcnt vmcnt(8)" ::: "memory"); \
      else if ((T) + 2 < NT) asm volatile("s_waitcnt vmcnt(4)" ::: "memory"); \
      else if ((T) + 1 < NT) asm volatile("s_waitcnt vmcnt(0)" ::: "memory"); \
      BAR();                                                                  \
    }                                                                         \
  }

  // bodies t = 1..NT-2 in pairs (b rename without copies), then final t = NT-1
  for (int tt = 1; tt + 2 < NT; tt += 2) {
    BODY(tt,     b0, b1, false);
    BODY(tt + 1, b1, b0, false);
  }
  BODY(NT - 1, b0, b1, true);
#undef BODY

  // pipeline drain: half2 of tile NT-1
  __builtin_amdgcn_s_setprio(1);
#pragma unroll
  for (int m = 0; m < 4; ++m)
#pragma unroll
    for (int n = 0; n < 4; ++n)
      acc[4 + m][n] = __builtin_amdgcn_mfma_f32_16x16x32_bf16(
          a1[m], b1[n], acc[4 + m][n], 0, 0, 0);
  __builtin_amdgcn_s_setprio(0);

  // ---- epilogue: C/D layout col=lane&15, row=(lane>>4)*4 + j ----
  const int rgrp = (lane >> 4) * 4;
  if (FUSE) {
    u16* H = (u16*)Cout;
    const int ew = (bn + wc * 64) >> 6;  // wave's 64-col span = exactly one expert
#pragma unroll
    for (int m = 0; m < 8; ++m) {
#pragma unroll
      for (int j = 0; j < 4; ++j) {
        const int grow = bm + wr * 128 + m * 16 + rgrp + j;
        const float mv = mask[(size_t)grow * NEXP + ew];
#pragma unroll
        for (int n = 0; n < 4; ++n) {
          const int gcol = bn + wc * 64 + n * 16 + fr;
          float v = acc[m][n][j];
          v = v / (1.0f + __expf(-v));   // silu
          H[(size_t)grow * N + gcol] = to_bf16(v * mv);
        }
      }
    }
  } else {
    float* O = (float*)Cout;
#pragma unroll
    for (int m = 0; m < 8; ++m) {
#pragma unroll
      for (int j = 0; j < 4; ++j) {
        const int grow = bm + wr * 128 + m * 16 + rgrp + j;
#pragma unroll
        for (int n = 0; n < 4; ++n) {
          const int gcol = bn + wc * 64 + n * 16 + fr;
          O[(size_t)grow * N + gcol] = acc[m][n][j];
        }
      }
    }
  }
}

extern "C" void kernel_launch(void* const* d_in, const int* in_sizes, int n_in,
                              void* d_out, int out_size, void* d_ws, size_t ws_size,
                              hipStream_t stream) {
  const float* x     = (const float*)d_in[0];
  const float* emask = (const float*)d_in[1];
  const float* w_up  = (const float*)d_in[2];
  const float* w_dn  = (const float*)d_in[3];
  float* out = (float*)d_out;

  // workspace (bf16): x[8192,2048] | w_up[4096,2048] | w_dn[2048,4096] | H[8192,4096]
  const size_t need = ((size_t)MT * DE + (size_t)ERDIM * DE + (size_t)DE * ERDIM +
                       (size_t)MT * ERDIM) * sizeof(u16);
  if (ws_size < need) return;

  u16* xb  = (u16*)d_ws;
  u16* wub = xb  + (size_t)MT * DE;
  u16* wdb = wub + (size_t)ERDIM * DE;
  u16* hb  = wdb + (size_t)DE * ERDIM;

  hipLaunchKernelGGL(cvt_f32_bf16, dim3(2048), dim3(256), 0, stream, x,    xb,  MT * DE);
  hipLaunchKernelGGL(cvt_f32_bf16, dim3(1024), dim3(256), 0, stream, w_up, wub, ERDIM * DE);
  hipLaunchKernelGGL(cvt_f32_bf16, dim3(1024), dim3(256), 0, stream, w_dn, wdb, DE * ERDIM);

  // GEMM1: H = silu(X @ Wup^T) * mask   [M=8192, N=4096, K=2048] -> 512 blocks
  hipLaunchKernelGGL((gemm_bt<1, DE>), dim3((MT / 256) * (ERDIM / 256)), dim3(512), 0, stream,
                     xb, wub, emask, (void*)hb, MT, ERDIM);
  // GEMM2: out = H @ Wdown^T             [M=8192, N=2048, K=4096] -> 256 blocks
  hipLaunchKernelGGL((gemm_bt<0, ERDIM>), dim3((MT / 256) * (DE / 256)), dim3(512), 0, stream,
                     hb, wdb, nullptr, (void*)out, MT, DE);
}

// Round 10
// 280.796 us; speedup vs baseline: 1.1082x; 1.0340x over previous
//
#include <hip/hip_runtime.h>
#include <hip/hip_bf16.h>

typedef unsigned short u16;
typedef unsigned int   u32;
typedef __attribute__((ext_vector_type(8))) short  s16x8;
typedef __attribute__((ext_vector_type(4))) float  f32x4;
typedef __attribute__((ext_vector_type(4))) unsigned short u16x4;

#define MT    8192   // B*S tokens
#define DE    2048   // embed dim
#define NEXP  64     // experts
#define ERDIM 4096   // experts * rank

__device__ __forceinline__ u16 to_bf16(float f) {
  u32 u = __builtin_bit_cast(u32, f);
  u32 r = u + 0x7fffu + ((u >> 16) & 1u);
  return (u16)(r >> 16);
}

__global__ void cvt_f32_bf16(const float* __restrict__ in, u16* __restrict__ out, int n) {
  const int stride = gridDim.x * blockDim.x;
  for (int i = blockIdx.x * blockDim.x + threadIdx.x; i * 4 < n; i += stride) {
    const float4 v = *reinterpret_cast<const float4*>(in + (size_t)i * 4);
    u16x4 o;
    o.x = to_bf16(v.x); o.y = to_bf16(v.y); o.z = to_bf16(v.z); o.w = to_bf16(v.w);
    *reinterpret_cast<u16x4*>(out + (size_t)i * 4) = o;
  }
}

#define GLDS(gp, lp) __builtin_amdgcn_global_load_lds(                        \
    (const __attribute__((address_space(1))) void*)(gp),                      \
    (__attribute__((address_space(3))) void*)(lp), 16, 0, 0)

#define BAR() do { asm volatile("" ::: "memory");                             \
                   __builtin_amdgcn_s_barrier();                              \
                   asm volatile("" ::: "memory"); } while (0)

// 8-phase 256x256 GEMM (m201-template port). C = A[M,K] * B[N,K]^T, bf16.
// BK=64, 2 LDS buffers (64KiB each; layout per buf: A [ks][256][32] @0,
// B [ks][256][32] @16384 elems), 8 waves (2M x 4N), per-wave out 128x64.
// Phase = one C-quadrant (rh,ch) x K=64 = 16 MFMA; reads {12,4,8,0}/phase;
// exactly one half-tile staged (2 GLDS) per phase; vmcnt(4) ONLY at P4/P8.
// Stage map (iter computes T,T+1): P1:A_H0(T+1->b1) P2:A_H1(T+1->b1)
// P3:B_H0(T+2->b0) P4:B_H1(T+2->b0) P5:A_H0(T+2->b0) P6:A_H1(T+2->b0)
// P7:B_H0(T+3->b1) P8:B_H1(T+3->b1).
// Race audit: each half staged >=1 barrier after all its readers' lgkm(0)
// completed (B(b0) reads end P2, staged P3+; A(b0) reads end P3(a_rh1 phase),
// staged P5+; B(b1) reads end P6, staged P7+; A(b1) reads end P7... A(b1,T-1)
// last read P7(prev), staged P1(cur) > P8(prev) barrier). Landing audit:
// vmcnt(4)@P4 retires {P7',P8',P1,P2} = B(T+1)+A(T+1) before P5 reads;
// vmcnt(4)@P8 retires {P3..P6} = B(T+2)+A(T+2) before P1' reads.
// LDS sub-layout per [ks][256][32] block == the R2/R3-proven conflict-free
// granule swizzle (store granule p at row r holds logical p^((r>>1)&3)).
template<int FUSE, int K>
__global__ __launch_bounds__(512, 2) void gemm_bt(
    const u16* __restrict__ A, const u16* __restrict__ Bm,
    const float* __restrict__ mask, void* __restrict__ Cout,
    const int M, const int N)
{
  constexpr int NT = K / 64;                 // K-tiles of 64 (NT even)
  __shared__ __align__(16) u16 lds[65536];   // 2 bufs x 32768 elems

  const int nbn = N / 256;
  const int nwg = (int)gridDim.x;
  const int cpx = nwg >> 3;
  const int bid = (int)blockIdx.x;
  const int swz = (bid & 7) * cpx + (bid >> 3);  // bijective XCD swizzle
  const int bm = (swz / nbn) * 256;
  const int bn = (swz % nbn) * 256;

  const int tid  = (int)threadIdx.x;
  const int lane = tid & 63;
  const int w    = tid >> 6;
  const int wr   = w >> 2;         // 0..1: 128-row group
  const int wc   = w & 3;          // 0..3: 64-col group

  const int fr = lane & 15;
  const int hi = lane >> 4;
  // lane-const read offset within a [256][32] ks-block (proven swizzle)
  const int rdc = fr * 32 + ((hi ^ ((fr >> 1) & 3)) * 8);

  // staging: thread covers row srow (0..127 within half), granule sq (inverse swz)
  const int srow = tid >> 2;
  const int sq   = (tid & 3) ^ ((srow >> 1) & 3);
  const u16* aR0 = A  + (size_t)(bm + srow) * K + sq * 8;        // A half0 rows
  const u16* aR1 = A  + (size_t)(bm + 128 + srow) * K + sq * 8;  // A half1
  const u16* bR0 = Bm + (size_t)(bn + srow) * K + sq * 8;
  const u16* bR1 = Bm + (size_t)(bn + 128 + srow) * K + sq * 8;

  // STG: one half-tile (both ksteps) = 2 GLDS. dest: buf d, region ro, half h.
#define STG(sp, T, d, ro, h) do {                                             \
    GLDS((sp) + (size_t)(T) * 64,                                             \
         lds + (d) * 32768 + (ro) + (h) * 4096 + tid * 8);                    \
    GLDS((sp) + (size_t)(T) * 64 + 32,                                        \
         lds + (d) * 32768 + (ro) + 8192 + (h) * 4096 + tid * 8);             \
  } while (0)

#define LDF(p) (*reinterpret_cast<const s16x8*>(p))

  f32x4 acc[8][4] = {};

  // ---- prologue: tile0 fully -> buf0; B halves of tile1 -> buf1 ----
  STG(aR0, 0, 0, 0, 0);      STG(aR1, 0, 0, 0, 1);
  STG(bR0, 0, 0, 16384, 0);  STG(bR1, 0, 0, 16384, 1);
  STG(bR0, 1, 1, 16384, 0);  STG(bR1, 1, 1, 16384, 1);
  asm volatile("s_waitcnt vmcnt(4)" ::: "memory");   // tile0 landed
  BAR();

  s16x8 af[4][2], bA[2][2], bB[2][2];

#define RD_A(bp, rh)                                                          \
    _Pragma("unroll") for (int m = 0; m < 4; ++m)                             \
    _Pragma("unroll") for (int ks = 0; ks < 2; ++ks)                          \
      af[m][ks] = LDF(&(bp)[ks * 8192 + (wr * 128 + (rh) * 64 + m * 16) * 32 + rdc]);
#define RD_B(bpB, dst, ch)                                                    \
    _Pragma("unroll") for (int n = 0; n < 2; ++n)                             \
    _Pragma("unroll") for (int ks = 0; ks < 2; ++ks)                          \
      dst[n][ks] = LDF(&(bpB)[ks * 8192 + (wc * 64 + ((ch) * 2 + n) * 16) * 32 + rdc]);
#define MFQ(mb, nb, bfr)                                                      \
    __builtin_amdgcn_s_setprio(1);                                            \
    _Pragma("unroll") for (int ks = 0; ks < 2; ++ks)                          \
    _Pragma("unroll") for (int m = 0; m < 4; ++m)                             \
    _Pragma("unroll") for (int n = 0; n < 2; ++n)                             \
      acc[(mb) + m][(nb) + n] = __builtin_amdgcn_mfma_f32_16x16x32_bf16(      \
          af[m][ks], bfr[n][ks], acc[(mb) + m][(nb) + n], 0, 0, 0);           \
    __builtin_amdgcn_s_setprio(0);
#define PH_IN()  do { BAR();                                                  \
    asm volatile("s_waitcnt lgkmcnt(0)" ::: "memory");                        \
    __builtin_amdgcn_sched_barrier(0); } while (0)

  for (int T = 0; T < NT; T += 2) {
    const u16* bp  = lds;                 // buf0 (tile T)
    const u16* bpB = lds + 16384;
    // ---- P1: Q(rh0,c0). reads a_rh0(8)+b_c0(4). stage A_H0(T+1)->b1 ----
    RD_A(bp, 0); RD_B(bpB, bA, 0);
    STG(aR0, T + 1, 1, 0, 0);
    asm volatile("s_waitcnt lgkmcnt(8)" ::: "memory");
    PH_IN(); MFQ(0, 0, bA); BAR();
    // ---- P2: Q(rh0,c1). reads b_c1(4). stage A_H1(T+1)->b1 ----
    RD_B(bpB, bB, 1);
    STG(aR1, T + 1, 1, 0, 1);
    PH_IN(); MFQ(0, 2, bB); BAR();
    // ---- P3: Q(rh1,c1). reads a_rh1(8). stage B_H0(T+2)->b0 ----
    RD_A(bp, 1);
    if (T + 2 < NT) STG(bR0, T + 2, 0, 16384, 0);
    PH_IN(); MFQ(4, 2, bB); BAR();
    // ---- P4: Q(rh1,c0). no reads. stage B_H1(T+2)->b0. vmcnt ----
    if (T + 2 < NT) { STG(bR1, T + 2, 0, 16384, 1);
                      asm volatile("s_waitcnt vmcnt(4)" ::: "memory"); }
    else            { asm volatile("s_waitcnt vmcnt(0)" ::: "memory"); }
    PH_IN(); MFQ(4, 0, bA); BAR();

    const u16* cp  = lds + 32768;         // buf1 (tile T+1)
    const u16* cpB = lds + 32768 + 16384;
    // ---- P5: Q(rh0,c0). stage A_H0(T+2)->b0 ----
    RD_A(cp, 0); RD_B(cpB, bA, 0);
    if (T + 2 < NT) STG(aR0, T + 2, 0, 0, 0);
    asm volatile("s_waitcnt lgkmcnt(8)" ::: "memory");
    PH_IN(); MFQ(0, 0, bA); BAR();
    // ---- P6: Q(rh0,c1). stage A_H1(T+2)->b0 ----
    RD_B(cpB, bB, 1);
    if (T + 2 < NT) STG(aR1, T + 2, 0, 0, 1);
    PH_IN(); MFQ(0, 2, bB); BAR();
    // ---- P7: Q(rh1,c1). stage B_H0(T+3)->b1 ----
    RD_A(cp, 1);
    if (T + 3 < NT) STG(bR0, T + 3, 1, 16384, 0);
    PH_IN(); MFQ(4, 2, bB); BAR();
    // ---- P8: Q(rh1,c0). stage B_H1(T+3)->b1. vmcnt ----
    if (T + 3 < NT) { STG(bR1, T + 3, 1, 16384, 1);
                      asm volatile("s_waitcnt vmcnt(4)" ::: "memory"); }
    else            { asm volatile("s_waitcnt vmcnt(0)" ::: "memory"); }
    PH_IN(); MFQ(4, 0, bA);
    if (T + 2 < NT) BAR();
  }
#undef STG
#undef LDF
#undef RD_A
#undef RD_B
#undef MFQ
#undef PH_IN

  // ---- epilogue: C/D layout col=lane&15, row=(lane>>4)*4 + j ----
  const int rgrp = hi * 4;
  if (FUSE) {
    u16* H = (u16*)Cout;
    const int ew = (bn + wc * 64) >> 6;  // wave's 64-col span = one expert
#pragma unroll
    for (int m = 0; m < 8; ++m) {
#pragma unroll
      for (int j = 0; j < 4; ++j) {
        const int grow = bm + wr * 128 + m * 16 + rgrp + j;
        const float mv = mask[(size_t)grow * NEXP + ew];
#pragma unroll
        for (int n = 0; n < 4; ++n) {
          const int gcol = bn + wc * 64 + n * 16 + fr;
          float v = acc[m][n][j];
          v = v / (1.0f + __expf(-v));   // silu
          H[(size_t)grow * N + gcol] = to_bf16(v * mv);
        }
      }
    }
  } else {
    float* O = (float*)Cout;
#pragma unroll
    for (int m = 0; m < 8; ++m) {
#pragma unroll
      for (int j = 0; j < 4; ++j) {
        const int grow = bm + wr * 128 + m * 16 + rgrp + j;
#pragma unroll
        for (int n = 0; n < 4; ++n) {
          const int gcol = bn + wc * 64 + n * 16 + fr;
          O[(size_t)grow * N + gcol] = acc[m][n][j];
        }
      }
    }
  }
}

extern "C" void kernel_launch(void* const* d_in, const int* in_sizes, int n_in,
                              void* d_out, int out_size, void* d_ws, size_t ws_size,
                              hipStream_t stream) {
  const float* x     = (const float*)d_in[0];
  const float* emask = (const float*)d_in[1];
  const float* w_up  = (const float*)d_in[2];
  const float* w_dn  = (const float*)d_in[3];
  float* out = (float*)d_out;

  // workspace (bf16): x[8192,2048] | w_up[4096,2048] | w_dn[2048,4096] | H[8192,4096]
  const size_t need = ((size_t)MT * DE + (size_t)ERDIM * DE + (size_t)DE * ERDIM +
                       (size_t)MT * ERDIM) * sizeof(u16);
  if (ws_size < need) return;

  u16* xb  = (u16*)d_ws;
  u16* wub = xb  + (size_t)MT * DE;
  u16* wdb = wub + (size_t)ERDIM * DE;
  u16* hb  = wdb + (size_t)DE * ERDIM;

  hipLaunchKernelGGL(cvt_f32_bf16, dim3(2048), dim3(256), 0, stream, x,    xb,  MT * DE);
  hipLaunchKernelGGL(cvt_f32_bf16, dim3(1024), dim3(256), 0, stream, w_up, wub, ERDIM * DE);
  hipLaunchKernelGGL(cvt_f32_bf16, dim3(1024), dim3(256), 0, stream, w_dn, wdb, DE * ERDIM);

  // GEMM1: H = silu(X @ Wup^T) * mask   [M=8192, N=4096, K=2048] -> 512 blocks
  hipLaunchKernelGGL((gemm_bt<1, DE>), dim3((MT / 256) * (ERDIM / 256)), dim3(512), 0, stream,
                     xb, wub, emask, (void*)hb, MT, ERDIM);
  // GEMM2: out = H @ Wdown^T             [M=8192, N=2048, K=4096] -> 256 blocks
  hipLaunchKernelGGL((gemm_bt<0, ERDIM>), dim3((MT / 256) * (DE / 256)), dim3(512), 0, stream,
                     hb, wdb, nullptr, (void*)out, MT, DE);
}